// Round 4
// baseline (292.290 us; speedup 1.0000x reference)
//
#include <hip/hip_runtime.h>

// Problem dims
#define NB 32
#define NA 64
#define SLEN 256
#define NH 128
#define RLEN 64
#define NE 16

typedef _Float16 f16;
typedef _Float16 f16x8 __attribute__((ext_vector_type(8)));
typedef _Float16 f16x4 __attribute__((ext_vector_type(4)));
typedef float f32x4 __attribute__((ext_vector_type(4)));

__device__ inline f16x8 cvt8(float4 a, float4 b) {
  f16x8 r;
  r[0] = (f16)a.x; r[1] = (f16)a.y; r[2] = (f16)a.z; r[3] = (f16)a.w;
  r[4] = (f16)b.x; r[5] = (f16)b.y; r[6] = (f16)b.z; r[7] = (f16)b.w;
  return r;
}

__device__ inline void gload_lds16(const float* g, float* l) {
  __builtin_amdgcn_global_load_lds((const __attribute__((address_space(1))) void*)g,
                                   (__attribute__((address_space(3))) void*)l, 16, 0, 0);
}

// ---------------------------------------------------------------------------
// K0: pack all GEMM weights into fp16 MFMA B-fragment order.
// packed[(kt*NT+nt)*512 + l*8 + t] = W[ro + kt*32 + (l>>4)*8 + t][nt*16 + (l&15)]
// ---------------------------------------------------------------------------
__global__ __launch_bounds__(256) void k0_pack(const float* __restrict__ re_w1,
                                               const float* __restrict__ re_w2,
                                               const float* __restrict__ se_w1,
                                               const float* __restrict__ se_w2,
                                               const float* __restrict__ ra_w,
                                               const float* __restrict__ ae_w1,
                                               f16* __restrict__ pk) {
  int idx = blockIdx.x * 256 + threadIdx.x;
  const float* src;
  int ro, N, ld, base;
  if (idx < 8192)        { src = re_w1; ro = 0;   N = 128; ld = 128; base = 0; }
  else if (idx < 40960)  { src = re_w2; ro = 0;   N = 256; ld = 256; base = 8192; }
  else if (idx < 73728)  { src = se_w1; ro = 0;   N = 128; ld = 128; base = 40960; }
  else if (idx < 90112)  { src = se_w2; ro = 0;   N = 128; ld = 128; base = 73728; }
  else if (idx < 106496) { src = re_w1; ro = 64;  N = 128; ld = 128; base = 90112; }
  else if (idx < 155648) { src = ra_w;  ro = 0;   N = 128; ld = 128; base = 106496; }
  else if (idx < 172032) { src = ae_w1; ro = 256; N = 128; ld = 128; base = 155648; }
  else if (idx < 188416) { src = ae_w1; ro = 384; N = 128; ld = 128; base = 172032; }
  else return;
  int li = idx - base;
  int t = li & 7, l = (li >> 3) & 63, rem = li >> 9;
  int NT = N >> 4;
  int nt = rem % NT, kt = rem / NT;
  int k = kt * 32 + (l >> 4) * 8 + t;
  int n = nt * 16 + (l & 15);
  pk[idx] = (f16)src[(size_t)(ro + k) * ld + n];
}

// ---------------------------------------------------------------------------
// K1m: MFMA s-MLP + sproj1. 64 rows per block, 4 waves.
// ---------------------------------------------------------------------------
__global__ __launch_bounds__(256) void k1m(const float* __restrict__ states,
                                           const float* __restrict__ se_b1,
                                           const float* __restrict__ se_b2,
                                           const float* __restrict__ re_b1,
                                           const f16* __restrict__ pse1,
                                           const f16* __restrict__ pse2,
                                           const f16* __restrict__ pre1b,
                                           float* __restrict__ s_out,
                                           float* __restrict__ sproj1) {
  __shared__ f16 t1[64 * 128];
  __shared__ f16 t2[64 * 128];
  const int row0 = blockIdx.x * 64;
  const int tid = threadIdx.x;
  const int w = tid >> 6, l = tid & 63, lr = l & 15, lh = l >> 4;

  f32x4 acc[4][2];
#pragma unroll
  for (int mt = 0; mt < 4; ++mt)
#pragma unroll
    for (int n = 0; n < 2; ++n) acc[mt][n] = (f32x4){0.f, 0.f, 0.f, 0.f};

  // layer1 K=256
#pragma unroll
  for (int kt = 0; kt < 8; ++kt) {
    f16x8 aF[4];
#pragma unroll
    for (int mt = 0; mt < 4; ++mt) {
      const float* p = states + (size_t)(row0 + mt * 16 + lr) * SLEN + kt * 32 + lh * 8;
      aF[mt] = cvt8(*(const float4*)p, *(const float4*)(p + 4));
    }
#pragma unroll
    for (int n = 0; n < 2; ++n) {
      f16x8 bF = *(const f16x8*)(pse1 + ((size_t)(kt * 8 + w * 2 + n) * 64 + l) * 8);
#pragma unroll
      for (int mt = 0; mt < 4; ++mt)
        acc[mt][n] = __builtin_amdgcn_mfma_f32_16x16x32_f16(aF[mt], bF, acc[mt][n], 0, 0, 0);
    }
  }
#pragma unroll
  for (int n = 0; n < 2; ++n) {
    int h = w * 32 + n * 16 + lr;
    float bias = se_b1[h];
#pragma unroll
    for (int mt = 0; mt < 4; ++mt)
#pragma unroll
      for (int reg = 0; reg < 4; ++reg) {
        int j = mt * 16 + lh * 4 + reg;
        float v = fmaxf(acc[mt][n][reg] + bias, 0.f);
        unsigned off = (unsigned)((j * NH + h) * 2) ^ ((unsigned)(j & 7) << 4);
        *(f16*)((char*)t1 + off) = (f16)v;
      }
  }
  __syncthreads();

  // layer2 K=128
#pragma unroll
  for (int mt = 0; mt < 4; ++mt)
#pragma unroll
    for (int n = 0; n < 2; ++n) acc[mt][n] = (f32x4){0.f, 0.f, 0.f, 0.f};
#pragma unroll
  for (int kt = 0; kt < 4; ++kt) {
    f16x8 aF[4];
#pragma unroll
    for (int mt = 0; mt < 4; ++mt) {
      int row = mt * 16 + lr;
      unsigned off = (unsigned)((row * NH + kt * 32 + lh * 8) * 2) ^ ((unsigned)(row & 7) << 4);
      aF[mt] = *(const f16x8*)((char*)t1 + off);
    }
#pragma unroll
    for (int n = 0; n < 2; ++n) {
      f16x8 bF = *(const f16x8*)(pse2 + ((size_t)(kt * 8 + w * 2 + n) * 64 + l) * 8);
#pragma unroll
      for (int mt = 0; mt < 4; ++mt)
        acc[mt][n] = __builtin_amdgcn_mfma_f32_16x16x32_f16(aF[mt], bF, acc[mt][n], 0, 0, 0);
    }
  }
#pragma unroll
  for (int n = 0; n < 2; ++n) {
    int h = w * 32 + n * 16 + lr;
    float bias = se_b2[h];
#pragma unroll
    for (int mt = 0; mt < 4; ++mt)
#pragma unroll
      for (int reg = 0; reg < 4; ++reg) {
        int j = mt * 16 + lh * 4 + reg;
        float v = fmaxf(acc[mt][n][reg] + bias, 0.f);
        s_out[(size_t)(row0 + j) * NH + h] = v;
        unsigned off = (unsigned)((j * NH + h) * 2) ^ ((unsigned)(j & 7) << 4);
        *(f16*)((char*)t2 + off) = (f16)v;
      }
  }
  __syncthreads();

  // proj K=128: sproj1 = s @ re_w1b + re_b1
#pragma unroll
  for (int mt = 0; mt < 4; ++mt)
#pragma unroll
    for (int n = 0; n < 2; ++n) acc[mt][n] = (f32x4){0.f, 0.f, 0.f, 0.f};
#pragma unroll
  for (int kt = 0; kt < 4; ++kt) {
    f16x8 aF[4];
#pragma unroll
    for (int mt = 0; mt < 4; ++mt) {
      int row = mt * 16 + lr;
      unsigned off = (unsigned)((row * NH + kt * 32 + lh * 8) * 2) ^ ((unsigned)(row & 7) << 4);
      aF[mt] = *(const f16x8*)((char*)t2 + off);
    }
#pragma unroll
    for (int n = 0; n < 2; ++n) {
      f16x8 bF = *(const f16x8*)(pre1b + ((size_t)(kt * 8 + w * 2 + n) * 64 + l) * 8);
#pragma unroll
      for (int mt = 0; mt < 4; ++mt)
        acc[mt][n] = __builtin_amdgcn_mfma_f32_16x16x32_f16(aF[mt], bF, acc[mt][n], 0, 0, 0);
    }
  }
#pragma unroll
  for (int n = 0; n < 2; ++n) {
    int h = w * 32 + n * 16 + lr;
    float bias = re_b1[h];
#pragma unroll
    for (int mt = 0; mt < 4; ++mt)
#pragma unroll
      for (int reg = 0; reg < 4; ++reg) {
        int j = mt * 16 + lh * 4 + reg;
        sproj1[(size_t)(row0 + j) * NH + h] = acc[mt][n][reg] + bias;
      }
  }
}

// ---------------------------------------------------------------------------
// K3 v2 (fixed staging): 2 (b,i) tiles per block, grid 1024.
// sp_lds staged via global_load_lds: 8 calls/wave x 1KiB = 32KiB exact.
// ---------------------------------------------------------------------------
__global__ __launch_bounds__(256, 3) void k3_rel(const float* __restrict__ relations,
                                                 const float* __restrict__ alive_mask,
                                                 const float* __restrict__ sproj1,
                                                 const float* __restrict__ re_b2,
                                                 const f16* __restrict__ pw1,
                                                 const f16* __restrict__ pw2,
                                                 const int* __restrict__ agent_id,
                                                 float* __restrict__ r_red,
                                                 f16* __restrict__ r_agent) {
  __shared__ f16 tl[64 * 128];       // 16 KB
  __shared__ float sp_lds[64 * 128]; // 32 KB
  __shared__ float alive[NA];
  const int bid = blockIdx.x;  // 0..1023
  const int b = bid >> 5;
  const int i0 = (bid & 31) * 2;
  const int tid = threadIdx.x;
  const int w = tid >> 6, l = tid & 63, lr = l & 15, lh = l >> 4;

  // preload sproj1[b] (64x128 f32 = 32KB) into LDS.
  // Each global_load_lds(16B) covers one wave's 64 lanes x 16B = 1KB.
  // Wave w covers floats [w*2048, (w+1)*2048) in 8 chunks of 256 floats.
  {
    const float* spb = sproj1 + (size_t)b * NA * NH;
#pragma unroll
    for (int it = 0; it < 8; ++it) {
      int off = w * 2048 + it * 256;
      gload_lds16(spb + off + l * 4, sp_lds + off);
    }
  }
  if (tid < 64) alive[tid] = alive_mask[b * NA + tid];
  float bz[4];
#pragma unroll
  for (int n = 0; n < 4; ++n) bz[n] = re_b2[w * 64 + n * 16 + lr];

  // B fragments for layer1 (shared across both tiles)
  f16x8 b1f[2][2];
#pragma unroll
  for (int kt = 0; kt < 2; ++kt)
#pragma unroll
    for (int n = 0; n < 2; ++n)
      b1f[kt][n] = *(const f16x8*)(pw1 + ((size_t)(kt * 8 + w * 2 + n) * 64 + l) * 8);

  // prefetch tile0 kt=0 raw f32
  float4 raw[4][2];
  const float* relp0 = relations + (size_t)(b * NA + i0) * NA * RLEN;
#pragma unroll
  for (int mt = 0; mt < 4; ++mt) {
    const float* p = relp0 + (mt * 16 + lr) * RLEN + lh * 8;
    raw[mt][0] = *(const float4*)p;
    raw[mt][1] = *(const float4*)(p + 4);
  }
  __syncthreads();  // sp_lds + alive ready (barrier drains vmcnt incl. lds loads)

  const int aid = agent_id[0];
  const bool domax = (w >= 2);

#pragma unroll
  for (int t = 0; t < 2; ++t) {
    const float* relp = relations + (size_t)(b * NA + i0 + t) * NA * RLEN;
    // layer1
    f32x4 acc1[4][2];
#pragma unroll
    for (int mt = 0; mt < 4; ++mt)
#pragma unroll
      for (int n = 0; n < 2; ++n) acc1[mt][n] = (f32x4){0.f, 0.f, 0.f, 0.f};

    // kt=0 from prefetched raw
    f16x8 aK[4];
#pragma unroll
    for (int mt = 0; mt < 4; ++mt) aK[mt] = cvt8(raw[mt][0], raw[mt][1]);
    // issue kt=1 loads
#pragma unroll
    for (int mt = 0; mt < 4; ++mt) {
      const float* p = relp + (mt * 16 + lr) * RLEN + 32 + lh * 8;
      raw[mt][0] = *(const float4*)p;
      raw[mt][1] = *(const float4*)(p + 4);
    }
#pragma unroll
    for (int mt = 0; mt < 4; ++mt)
#pragma unroll
      for (int n = 0; n < 2; ++n)
        acc1[mt][n] = __builtin_amdgcn_mfma_f32_16x16x32_f16(aK[mt], b1f[0][n], acc1[mt][n], 0, 0, 0);
    // kt=1
#pragma unroll
    for (int mt = 0; mt < 4; ++mt) aK[mt] = cvt8(raw[mt][0], raw[mt][1]);
    if (t == 0) {  // prefetch tile1 kt=0
      const float* relp1 = relations + (size_t)(b * NA + i0 + 1) * NA * RLEN;
#pragma unroll
      for (int mt = 0; mt < 4; ++mt) {
        const float* p = relp1 + (mt * 16 + lr) * RLEN + lh * 8;
        raw[mt][0] = *(const float4*)p;
        raw[mt][1] = *(const float4*)(p + 4);
      }
    }
#pragma unroll
    for (int mt = 0; mt < 4; ++mt)
#pragma unroll
      for (int n = 0; n < 2; ++n)
        acc1[mt][n] = __builtin_amdgcn_mfma_f32_16x16x32_f16(aK[mt], b1f[1][n], acc1[mt][n], 0, 0, 0);

    // epilogue1: + sproj1 (re_b1 folded), relu, fp16 swizzled LDS
#pragma unroll
    for (int mt = 0; mt < 4; ++mt)
#pragma unroll
      for (int n = 0; n < 2; ++n) {
        int h = w * 32 + n * 16 + lr;
#pragma unroll
        for (int reg = 0; reg < 4; ++reg) {
          int j = mt * 16 + lh * 4 + reg;
          float v = fmaxf(acc1[mt][n][reg] + sp_lds[j * NH + h], 0.f);
          unsigned off = (unsigned)((j * NH + h) * 2) ^ ((unsigned)(j & 7) << 4);
          *(f16*)((char*)tl + off) = (f16)v;
        }
      }
    __syncthreads();

    // layer2: wave w owns output cols [w*64, w*64+64)
    f32x4 acc2[4][4];
#pragma unroll
    for (int mt = 0; mt < 4; ++mt)
#pragma unroll
      for (int n = 0; n < 4; ++n) acc2[mt][n] = (f32x4){0.f, 0.f, 0.f, 0.f};
#pragma unroll
    for (int kt2 = 0; kt2 < 4; ++kt2) {
      f16x8 a2[4];
#pragma unroll
      for (int mt = 0; mt < 4; ++mt) {
        int row = mt * 16 + lr;
        unsigned off = (unsigned)((row * 256 + kt2 * 64 + lh * 16)) ^ ((unsigned)(row & 7) << 4);
        a2[mt] = *(const f16x8*)((char*)tl + off);
      }
      f16x8 b2f[4];
#pragma unroll
      for (int n = 0; n < 4; ++n)
        b2f[n] = *(const f16x8*)(pw2 + ((size_t)(kt2 * 16 + w * 4 + n) * 64 + l) * 8);
#pragma unroll
      for (int mt = 0; mt < 4; ++mt)
#pragma unroll
        for (int n = 0; n < 4; ++n)
          acc2[mt][n] = __builtin_amdgcn_mfma_f32_16x16x32_f16(a2[mt], b2f[n], acc2[mt][n], 0, 0, 0);
    }

    // epilogue2
    const bool isagent = (i0 + t == aid);
    float red[4];
#pragma unroll
    for (int n = 0; n < 4; ++n) red[n] = 0.f;
#pragma unroll
    for (int n = 0; n < 4; ++n) {
      int col = w * 64 + n * 16 + lr;
      float bias = bz[n];
#pragma unroll
      for (int mt = 0; mt < 4; ++mt)
#pragma unroll
        for (int reg = 0; reg < 4; ++reg) {
          int j = mt * 16 + lh * 4 + reg;
          float rv = fmaxf(acc2[mt][n][reg] + bias, 0.f);
          float rm = rv * alive[j];
          red[n] = domax ? fmaxf(red[n], rm) : (red[n] + rm);
          if (isagent) r_agent[((size_t)b * NA + j) * 256 + col] = (f16)rv;
        }
    }
#pragma unroll
    for (int n = 0; n < 4; ++n) {
      float v = red[n];
      float v1 = __shfl_xor(v, 16, 64);
      v = domax ? fmaxf(v, v1) : v + v1;
      float v2 = __shfl_xor(v, 32, 64);
      v = domax ? fmaxf(v, v2) : v + v2;
      if (lh == 0) r_red[(size_t)(b * NA + i0 + t) * 256 + w * 64 + n * 16 + lr] = v;
    }
    __syncthreads();  // tl free for next tile
  }
}

// ---------------------------------------------------------------------------
// K4m: 64 rows per block.
//   s_new  = relu([s, r_avr, r_max] @ ra_w + ra_b)   K=384
//   sproj2 = s_new @ ae_w1[256:384]; sproj3 = s_new @ ae_w1[384:512]
// ---------------------------------------------------------------------------
__global__ __launch_bounds__(256) void k4m(const float* __restrict__ s,
                                           const float* __restrict__ r_red,
                                           const float* __restrict__ ra_b,
                                           const f16* __restrict__ pra,
                                           const f16* __restrict__ pae1b,
                                           const f16* __restrict__ pae1c,
                                           float* __restrict__ s_new,
                                           float* __restrict__ sproj2,
                                           float* __restrict__ sproj3) {
  __shared__ f16 x3[64 * 384];  // 48 KB
  __shared__ f16 t2[64 * 128];  // 16 KB
  const int row0 = blockIdx.x * 64;
  const int tid = threadIdx.x;
  const int w = tid >> 6, l = tid & 63, lr = l & 15, lh = l >> 4;

  // stage X = [s | r_avr | r_max] as fp16 swizzled
#pragma unroll
  for (int it = 0; it < 24; ++it) {
    int e = it * 1024 + tid * 4;
    int row = e / 384;
    int c = e - row * 384;
    float4 v;
    if (c < 128) {
      v = *(const float4*)(s + (size_t)(row0 + row) * NH + c);
    } else {
      v = *(const float4*)(r_red + (size_t)(row0 + row) * 256 + (c - 128));
      if (c < 256) { v.x *= (1.f / 64.f); v.y *= (1.f / 64.f); v.z *= (1.f / 64.f); v.w *= (1.f / 64.f); }
    }
    f16x4 hv;
    hv[0] = (f16)v.x; hv[1] = (f16)v.y; hv[2] = (f16)v.z; hv[3] = (f16)v.w;
    unsigned off = (unsigned)((row * 384 + c) * 2) ^ ((unsigned)(row & 7) << 4);
    *(f16x4*)((char*)x3 + off) = hv;
  }
  __syncthreads();

  // ra layer K=384
  f32x4 acc[4][2];
#pragma unroll
  for (int mt = 0; mt < 4; ++mt)
#pragma unroll
    for (int n = 0; n < 2; ++n) acc[mt][n] = (f32x4){0.f, 0.f, 0.f, 0.f};
#pragma unroll
  for (int kt = 0; kt < 12; ++kt) {
    f16x8 aF[4];
#pragma unroll
    for (int mt = 0; mt < 4; ++mt) {
      int row = mt * 16 + lr;
      unsigned off = (unsigned)((row * 384 + kt * 32 + lh * 8) * 2) ^ ((unsigned)(row & 7) << 4);
      aF[mt] = *(const f16x8*)((char*)x3 + off);
    }
#pragma unroll
    for (int n = 0; n < 2; ++n) {
      f16x8 bF = *(const f16x8*)(pra + ((size_t)(kt * 8 + w * 2 + n) * 64 + l) * 8);
#pragma unroll
      for (int mt = 0; mt < 4; ++mt)
        acc[mt][n] = __builtin_amdgcn_mfma_f32_16x16x32_f16(aF[mt], bF, acc[mt][n], 0, 0, 0);
    }
  }
#pragma unroll
  for (int n = 0; n < 2; ++n) {
    int h = w * 32 + n * 16 + lr;
    float bias = ra_b[h];
#pragma unroll
    for (int mt = 0; mt < 4; ++mt)
#pragma unroll
      for (int reg = 0; reg < 4; ++reg) {
        int j = mt * 16 + lh * 4 + reg;
        float v = fmaxf(acc[mt][n][reg] + bias, 0.f);
        s_new[(size_t)(row0 + j) * NH + h] = v;
        unsigned off = (unsigned)((j * NH + h) * 2) ^ ((unsigned)(j & 7) << 4);
        *(f16*)((char*)t2 + off) = (f16)v;
      }
  }
  __syncthreads();

  // proj2/proj3 K=128 (shared A fragments)
  f32x4 p2[4][2], p3[4][2];
#pragma unroll
  for (int mt = 0; mt < 4; ++mt)
#pragma unroll
    for (int n = 0; n < 2; ++n) { p2[mt][n] = (f32x4){0.f, 0.f, 0.f, 0.f}; p3[mt][n] = (f32x4){0.f, 0.f, 0.f, 0.f}; }
#pragma unroll
  for (int kt = 0; kt < 4; ++kt) {
    f16x8 aF[4];
#pragma unroll
    for (int mt = 0; mt < 4; ++mt) {
      int row = mt * 16 + lr;
      unsigned off = (unsigned)((row * NH + kt * 32 + lh * 8) * 2) ^ ((unsigned)(row & 7) << 4);
      aF[mt] = *(const f16x8*)((char*)t2 + off);
    }
#pragma unroll
    for (int n = 0; n < 2; ++n) {
      f16x8 b2 = *(const f16x8*)(pae1b + ((size_t)(kt * 8 + w * 2 + n) * 64 + l) * 8);
      f16x8 b3 = *(const f16x8*)(pae1c + ((size_t)(kt * 8 + w * 2 + n) * 64 + l) * 8);
#pragma unroll
      for (int mt = 0; mt < 4; ++mt) {
        p2[mt][n] = __builtin_amdgcn_mfma_f32_16x16x32_f16(aF[mt], b2, p2[mt][n], 0, 0, 0);
        p3[mt][n] = __builtin_amdgcn_mfma_f32_16x16x32_f16(aF[mt], b3, p3[mt][n], 0, 0, 0);
      }
    }
  }
#pragma unroll
  for (int n = 0; n < 2; ++n) {
    int h = w * 32 + n * 16 + lr;
#pragma unroll
    for (int mt = 0; mt < 4; ++mt)
#pragma unroll
      for (int reg = 0; reg < 4; ++reg) {
        int j = mt * 16 + lh * 4 + reg;
        sproj2[(size_t)(row0 + j) * NH + h] = p2[mt][n][reg];
        sproj3[(size_t)(row0 + j) * NH + h] = p3[mt][n][reg];
      }
  }
}

// ---------------------------------------------------------------------------
// K5a: per b, compute sel row and passive row. One block per b.
// ---------------------------------------------------------------------------
__global__ __launch_bounds__(128) void k5a_sel(const float* __restrict__ ae_w1,
                                               const float* __restrict__ ae_b1,
                                               const float* __restrict__ ae_w2,
                                               const float* __restrict__ ae_b2,
                                               const float* __restrict__ action_embed,
                                               const int* __restrict__ action,
                                               const int* __restrict__ agent_id,
                                               const f16* __restrict__ r_agent,
                                               const float* __restrict__ sproj2,
                                               const float* __restrict__ sproj3,
                                               float* __restrict__ sel_ws,
                                               float* __restrict__ passive_ws,
                                               float* __restrict__ out_sel) {
  __shared__ float rr[256];
  __shared__ float t[NH];
  const int b = blockIdx.x;
  const int h = threadIdx.x;
  const int act = action[b];
  const int aid = agent_id[0];
  if (act < NE) {
    float sv = action_embed[act * NH + h];
    sel_ws[b * NH + h] = sv;
    out_sel[b * NH + h] = sv;
    passive_ws[b * NH + h] = 0.f;
    return;
  }
  const int jj = act - NE;
  const int row = b * NA + jj;
  const int arow = b * NA + aid;
  rr[h] = (float)r_agent[(size_t)row * 256 + h];
  rr[128 + h] = (float)r_agent[(size_t)row * 256 + 128 + h];
  __syncthreads();
  float acc = ae_b1[h] + sproj2[(size_t)row * NH + h] + sproj3[(size_t)arow * NH + h];
#pragma unroll 4
  for (int k = 0; k < 256; ++k) acc += rr[k] * ae_w1[k * NH + h];
  float u = fmaxf(acc, 0.f);
  t[h] = u;
  __syncthreads();
  float a_act = ae_b2[h], a_pas = ae_b2[128 + h];
#pragma unroll 4
  for (int k = 0; k < NH; ++k) {
    float tv = t[k];
    a_act += tv * ae_w2[k * 256 + h];
    a_pas += tv * ae_w2[k * 256 + 128 + h];
  }
  a_act = fmaxf(a_act, 0.f);
  a_pas = fmaxf(a_pas, 0.f);
  sel_ws[b * NH + h] = a_act;
  out_sel[b * NH + h] = a_act;
  passive_ws[b * NH + h] = a_pas;
}

// ---------------------------------------------------------------------------
// K5b: assemble state and passive_sel outputs (float4 vectorized).
// ---------------------------------------------------------------------------
__global__ __launch_bounds__(256) void k5b_out(const float* __restrict__ s_new,
                                               const float* __restrict__ sel_ws,
                                               const float* __restrict__ passive_ws,
                                               const int* __restrict__ action,
                                               const int* __restrict__ agent_id,
                                               float* __restrict__ out_state,
                                               float* __restrict__ out_passive) {
  int q = blockIdx.x * 256 + threadIdx.x;  // float4 index, 65536 total
  int idx = q * 4;
  int h = idx & 127;
  int row = idx >> 7;
  int b = row >> 6, i = row & 63;
  int act = action[b];
  int aid = agent_id[0];
  float4 st = *(const float4*)(s_new + idx);
  float4 ps = {0.f, 0.f, 0.f, 0.f};
  if (act >= NE && i == act - NE) {
    ps = *(const float4*)(passive_ws + b * NH + h);
    st.x += ps.x; st.y += ps.y; st.z += ps.z; st.w += ps.w;
  }
  if (i == aid) {
    float4 sl = *(const float4*)(sel_ws + b * NH + h);
    st.x += sl.x; st.y += sl.y; st.z += sl.z; st.w += sl.w;
  }
  *(float4*)(out_state + idx) = st;
  *(float4*)(out_passive + idx) = ps;
}

// ---------------------------------------------------------------------------
extern "C" void kernel_launch(void* const* d_in, const int* in_sizes, int n_in,
                              void* d_out, int out_size, void* d_ws, size_t ws_size,
                              hipStream_t stream) {
  (void)in_sizes; (void)n_in; (void)out_size; (void)ws_size;
  const float* states       = (const float*)d_in[0];
  const float* relations    = (const float*)d_in[1];
  const float* alive_mask   = (const float*)d_in[2];
  const float* se_w1        = (const float*)d_in[3];
  const float* se_b1        = (const float*)d_in[4];
  const float* se_w2        = (const float*)d_in[5];
  const float* se_b2        = (const float*)d_in[6];
  const float* re_w1        = (const float*)d_in[7];
  const float* re_b1        = (const float*)d_in[8];
  const float* re_w2        = (const float*)d_in[9];
  const float* re_b2        = (const float*)d_in[10];
  const float* ra_w         = (const float*)d_in[11];
  const float* ra_b         = (const float*)d_in[12];
  const float* ae_w1        = (const float*)d_in[13];
  const float* ae_b1        = (const float*)d_in[14];
  const float* ae_w2        = (const float*)d_in[15];
  const float* ae_b2        = (const float*)d_in[16];
  const float* action_embed = (const float*)d_in[17];
  const int*   action       = (const int*)d_in[19];
  const int*   agent_id     = (const int*)d_in[20];
  float* out = (float*)d_out;

  // workspace layout (float elements)
  float* wsf       = (float*)d_ws;
  float* s         = wsf;                // 2048*128
  float* sproj1    = wsf + 262144;       // 2048*128
  float* r_red     = wsf + 524288;       // 2048*256 (sum | max)
  float* s_new     = wsf + 1048576;      // 2048*128
  float* sproj2    = wsf + 1310720;      // 2048*128
  float* sproj3    = wsf + 1572864;      // 2048*128
  float* sel_ws    = wsf + 1835008;      // 32*128
  float* passive_ws= wsf + 1839104;      // 32*128
  f16*   wsh       = (f16*)(wsf + 1843200);
  f16*   r_agent   = wsh;                // 32*64*256
  f16*   pk        = wsh + 524288;       // 188416 packed weights
  f16*   pw_re1a   = pk;
  f16*   pw_re2    = pk + 8192;
  f16*   pw_se1    = pk + 40960;
  f16*   pw_se2    = pk + 73728;
  f16*   pw_re1b   = pk + 90112;
  f16*   pw_ra     = pk + 106496;
  f16*   pw_ae1b   = pk + 155648;
  f16*   pw_ae1c   = pk + 172032;

  k0_pack<<<736, 256, 0, stream>>>(re_w1, re_w2, se_w1, se_w2, ra_w, ae_w1, pk);
  k1m<<<32, 256, 0, stream>>>(states, se_b1, se_b2, re_b1, pw_se1, pw_se2, pw_re1b,
                              s, sproj1);
  k3_rel<<<1024, 256, 0, stream>>>(relations, alive_mask, sproj1, re_b2, pw_re1a, pw_re2,
                                   agent_id, r_red, r_agent);
  k4m<<<32, 256, 0, stream>>>(s, r_red, ra_b, pw_ra, pw_ae1b, pw_ae1c,
                              s_new, sproj2, sproj3);
  k5a_sel<<<32, 128, 0, stream>>>(ae_w1, ae_b1, ae_w2, ae_b2, action_embed, action,
                                  agent_id, r_agent, sproj2, sproj3, sel_ws, passive_ws,
                                  out + 262144);
  k5b_out<<<256, 256, 0, stream>>>(s_new, sel_ws, passive_ws, action, agent_id,
                                   out, out + 266240);
}

// Round 5
// 191.379 us; speedup vs baseline: 1.5273x; 1.5273x over previous
//
#include <hip/hip_runtime.h>

// Problem dims
#define NB 32
#define NA 64
#define SLEN 256
#define NH 128
#define RLEN 64
#define NE 16

typedef _Float16 f16;
typedef _Float16 f16x8 __attribute__((ext_vector_type(8)));
typedef _Float16 f16x4 __attribute__((ext_vector_type(4)));
typedef float f32x4 __attribute__((ext_vector_type(4)));

__device__ inline f16x8 cvt8(float4 a, float4 b) {
  f16x8 r;
  r[0] = (f16)a.x; r[1] = (f16)a.y; r[2] = (f16)a.z; r[3] = (f16)a.w;
  r[4] = (f16)b.x; r[5] = (f16)b.y; r[6] = (f16)b.z; r[7] = (f16)b.w;
  return r;
}

__device__ inline void gload_lds16(const float* g, float* l) {
  __builtin_amdgcn_global_load_lds((const __attribute__((address_space(1))) void*)g,
                                   (__attribute__((address_space(3))) void*)l, 16, 0, 0);
}

// ---------------------------------------------------------------------------
// K0: pack all GEMM weights into fp16 MFMA B-fragment order.
// packed[(kt*NT+nt)*512 + l*8 + t] = W[ro + kt*32 + (l>>4)*8 + t][nt*16 + (l&15)]
// ---------------------------------------------------------------------------
__global__ __launch_bounds__(256) void k0_pack(const float* __restrict__ re_w1,
                                               const float* __restrict__ re_w2,
                                               const float* __restrict__ se_w1,
                                               const float* __restrict__ se_w2,
                                               const float* __restrict__ ra_w,
                                               const float* __restrict__ ae_w1,
                                               f16* __restrict__ pk) {
  int idx = blockIdx.x * 256 + threadIdx.x;
  const float* src;
  int ro, N, ld, base;
  if (idx < 8192)        { src = re_w1; ro = 0;   N = 128; ld = 128; base = 0; }
  else if (idx < 40960)  { src = re_w2; ro = 0;   N = 256; ld = 256; base = 8192; }
  else if (idx < 73728)  { src = se_w1; ro = 0;   N = 128; ld = 128; base = 40960; }
  else if (idx < 90112)  { src = se_w2; ro = 0;   N = 128; ld = 128; base = 73728; }
  else if (idx < 106496) { src = re_w1; ro = 64;  N = 128; ld = 128; base = 90112; }
  else if (idx < 155648) { src = ra_w;  ro = 0;   N = 128; ld = 128; base = 106496; }
  else if (idx < 172032) { src = ae_w1; ro = 256; N = 128; ld = 128; base = 155648; }
  else if (idx < 188416) { src = ae_w1; ro = 384; N = 128; ld = 128; base = 172032; }
  else return;
  int li = idx - base;
  int t = li & 7, l = (li >> 3) & 63, rem = li >> 9;
  int NT = N >> 4;
  int nt = rem % NT, kt = rem / NT;
  int k = kt * 32 + (l >> 4) * 8 + t;
  int n = nt * 16 + (l & 15);
  pk[idx] = (f16)src[(size_t)(ro + k) * ld + n];
}

// ---------------------------------------------------------------------------
// K1m: s-MLP + sproj1. 16 rows per block, grid 128, 4 waves.
//   t = relu(states @ se_w1 + se_b1)   K=256
//   s = relu(t @ se_w2 + se_b2)        K=128
//   sproj1 = s @ re_w1[64:192] + re_b1 K=128
// ---------------------------------------------------------------------------
__global__ __launch_bounds__(256) void k1m(const float* __restrict__ states,
                                           const float* __restrict__ se_b1,
                                           const float* __restrict__ se_b2,
                                           const float* __restrict__ re_b1,
                                           const f16* __restrict__ pse1,
                                           const f16* __restrict__ pse2,
                                           const f16* __restrict__ pre1b,
                                           float* __restrict__ s_out,
                                           float* __restrict__ sproj1) {
  __shared__ f16 t1[16 * 128];
  __shared__ f16 t2[16 * 128];
  const int row0 = blockIdx.x * 16;
  const int tid = threadIdx.x;
  const int w = tid >> 6, l = tid & 63, lr = l & 15, lh = l >> 4;

  f32x4 acc[2];
  acc[0] = (f32x4){0.f, 0.f, 0.f, 0.f};
  acc[1] = (f32x4){0.f, 0.f, 0.f, 0.f};

  // layer1 K=256
#pragma unroll
  for (int kt = 0; kt < 8; ++kt) {
    const float* p = states + (size_t)(row0 + lr) * SLEN + kt * 32 + lh * 8;
    f16x8 aF = cvt8(*(const float4*)p, *(const float4*)(p + 4));
#pragma unroll
    for (int n = 0; n < 2; ++n) {
      f16x8 bF = *(const f16x8*)(pse1 + ((size_t)(kt * 8 + w * 2 + n) * 64 + l) * 8);
      acc[n] = __builtin_amdgcn_mfma_f32_16x16x32_f16(aF, bF, acc[n], 0, 0, 0);
    }
  }
#pragma unroll
  for (int n = 0; n < 2; ++n) {
    int h = w * 32 + n * 16 + lr;
    float bias = se_b1[h];
#pragma unroll
    for (int reg = 0; reg < 4; ++reg) {
      int j = lh * 4 + reg;
      float v = fmaxf(acc[n][reg] + bias, 0.f);
      unsigned off = (unsigned)((j * NH + h) * 2) ^ ((unsigned)(j & 7) << 4);
      *(f16*)((char*)t1 + off) = (f16)v;
    }
  }
  __syncthreads();

  // layer2 K=128
  acc[0] = (f32x4){0.f, 0.f, 0.f, 0.f};
  acc[1] = (f32x4){0.f, 0.f, 0.f, 0.f};
#pragma unroll
  for (int kt = 0; kt < 4; ++kt) {
    unsigned off = (unsigned)((lr * NH + kt * 32 + lh * 8) * 2) ^ ((unsigned)(lr & 7) << 4);
    f16x8 aF = *(const f16x8*)((char*)t1 + off);
#pragma unroll
    for (int n = 0; n < 2; ++n) {
      f16x8 bF = *(const f16x8*)(pse2 + ((size_t)(kt * 8 + w * 2 + n) * 64 + l) * 8);
      acc[n] = __builtin_amdgcn_mfma_f32_16x16x32_f16(aF, bF, acc[n], 0, 0, 0);
    }
  }
#pragma unroll
  for (int n = 0; n < 2; ++n) {
    int h = w * 32 + n * 16 + lr;
    float bias = se_b2[h];
#pragma unroll
    for (int reg = 0; reg < 4; ++reg) {
      int j = lh * 4 + reg;
      float v = fmaxf(acc[n][reg] + bias, 0.f);
      s_out[(size_t)(row0 + j) * NH + h] = v;
      unsigned off = (unsigned)((j * NH + h) * 2) ^ ((unsigned)(j & 7) << 4);
      *(f16*)((char*)t2 + off) = (f16)v;
    }
  }
  __syncthreads();

  // proj K=128: sproj1 = s @ re_w1b + re_b1
  acc[0] = (f32x4){0.f, 0.f, 0.f, 0.f};
  acc[1] = (f32x4){0.f, 0.f, 0.f, 0.f};
#pragma unroll
  for (int kt = 0; kt < 4; ++kt) {
    unsigned off = (unsigned)((lr * NH + kt * 32 + lh * 8) * 2) ^ ((unsigned)(lr & 7) << 4);
    f16x8 aF = *(const f16x8*)((char*)t2 + off);
#pragma unroll
    for (int n = 0; n < 2; ++n) {
      f16x8 bF = *(const f16x8*)(pre1b + ((size_t)(kt * 8 + w * 2 + n) * 64 + l) * 8);
      acc[n] = __builtin_amdgcn_mfma_f32_16x16x32_f16(aF, bF, acc[n], 0, 0, 0);
    }
  }
#pragma unroll
  for (int n = 0; n < 2; ++n) {
    int h = w * 32 + n * 16 + lr;
    float bias = re_b1[h];
#pragma unroll
    for (int reg = 0; reg < 4; ++reg) {
      int j = lh * 4 + reg;
      sproj1[(size_t)(row0 + j) * NH + h] = acc[n][reg] + bias;
    }
  }
}

// ---------------------------------------------------------------------------
// K3 v3: one (b,i) tile per block, grid 2048. sproj1 staged to LDS via
// global_load_lds (verified pattern). No min-wave bound -> no spill.
// ---------------------------------------------------------------------------
__global__ __launch_bounds__(256) void k3_rel(const float* __restrict__ relations,
                                              const float* __restrict__ alive_mask,
                                              const float* __restrict__ sproj1,
                                              const float* __restrict__ re_b2,
                                              const f16* __restrict__ pw1,
                                              const f16* __restrict__ pw2,
                                              const int* __restrict__ agent_id,
                                              float* __restrict__ r_red,
                                              f16* __restrict__ r_agent) {
  __shared__ f16 tl[64 * 128];       // 16 KB
  __shared__ float sp_lds[64 * 128]; // 32 KB
  __shared__ float alive[NA];
  const int bid = blockIdx.x;  // 0..2047
  const int b = bid >> 6, i = bid & 63;
  const int tid = threadIdx.x;
  const int w = tid >> 6, l = tid & 63, lr = l & 15, lh = l >> 4;

  // stage sproj1[b] (64x128 f32 = 32KB): 8 gload_lds16 per wave, 1KB each.
  {
    const float* spb = sproj1 + (size_t)b * NA * NH;
#pragma unroll
    for (int it = 0; it < 8; ++it) {
      int off = w * 2048 + it * 256;
      gload_lds16(spb + off + l * 4, sp_lds + off);
    }
  }
  if (tid < 64) alive[tid] = alive_mask[b * NA + tid];
  float bz[4];
#pragma unroll
  for (int n = 0; n < 4; ++n) bz[n] = re_b2[w * 64 + n * 16 + lr];

  // layer1 inputs: relations rows + B fragments
  const float* relp = relations + (size_t)bid * NA * RLEN;
  f16x8 a1[4][2];
#pragma unroll
  for (int mt = 0; mt < 4; ++mt)
#pragma unroll
    for (int kt = 0; kt < 2; ++kt) {
      const float* p = relp + (mt * 16 + lr) * RLEN + kt * 32 + lh * 8;
      a1[mt][kt] = cvt8(*(const float4*)p, *(const float4*)(p + 4));
    }
  f16x8 b1f[2][2];
#pragma unroll
  for (int kt = 0; kt < 2; ++kt)
#pragma unroll
    for (int n = 0; n < 2; ++n)
      b1f[kt][n] = *(const f16x8*)(pw1 + ((size_t)(kt * 8 + w * 2 + n) * 64 + l) * 8);

  f32x4 acc1[4][2];
#pragma unroll
  for (int mt = 0; mt < 4; ++mt)
#pragma unroll
    for (int n = 0; n < 2; ++n) acc1[mt][n] = (f32x4){0.f, 0.f, 0.f, 0.f};
#pragma unroll
  for (int kt = 0; kt < 2; ++kt)
#pragma unroll
    for (int mt = 0; mt < 4; ++mt)
#pragma unroll
      for (int n = 0; n < 2; ++n)
        acc1[mt][n] = __builtin_amdgcn_mfma_f32_16x16x32_f16(a1[mt][kt], b1f[kt][n],
                                                             acc1[mt][n], 0, 0, 0);
  __syncthreads();  // sp_lds + alive ready (barrier drains global_load_lds)

  // epilogue1: + sproj1 (re_b1 folded), relu, fp16 swizzled LDS
#pragma unroll
  for (int mt = 0; mt < 4; ++mt)
#pragma unroll
    for (int n = 0; n < 2; ++n) {
      int h = w * 32 + n * 16 + lr;
#pragma unroll
      for (int reg = 0; reg < 4; ++reg) {
        int j = mt * 16 + lh * 4 + reg;
        float v = fmaxf(acc1[mt][n][reg] + sp_lds[j * NH + h], 0.f);
        unsigned off = (unsigned)((j * NH + h) * 2) ^ ((unsigned)(j & 7) << 4);
        *(f16*)((char*)tl + off) = (f16)v;
      }
    }
  __syncthreads();

  // layer2: wave w owns output cols [w*64, w*64+64)
  f32x4 acc2[4][4];
#pragma unroll
  for (int mt = 0; mt < 4; ++mt)
#pragma unroll
    for (int n = 0; n < 4; ++n) acc2[mt][n] = (f32x4){0.f, 0.f, 0.f, 0.f};
#pragma unroll
  for (int kt2 = 0; kt2 < 4; ++kt2) {
    f16x8 a2[4];
#pragma unroll
    for (int mt = 0; mt < 4; ++mt) {
      int row = mt * 16 + lr;
      unsigned off = (unsigned)((row * 256 + kt2 * 64 + lh * 16)) ^ ((unsigned)(row & 7) << 4);
      a2[mt] = *(const f16x8*)((char*)tl + off);
    }
    f16x8 b2f[4];
#pragma unroll
    for (int n = 0; n < 4; ++n)
      b2f[n] = *(const f16x8*)(pw2 + ((size_t)(kt2 * 16 + w * 4 + n) * 64 + l) * 8);
#pragma unroll
    for (int mt = 0; mt < 4; ++mt)
#pragma unroll
      for (int n = 0; n < 4; ++n)
        acc2[mt][n] = __builtin_amdgcn_mfma_f32_16x16x32_f16(a2[mt], b2f[n], acc2[mt][n], 0, 0, 0);
  }

  // epilogue2: bias+relu, masked sum/max over j, agent slice store
  const int aid = agent_id[0];
  const bool isagent = (i == aid);
  const bool domax = (w >= 2);
  float red[4];
#pragma unroll
  for (int n = 0; n < 4; ++n) red[n] = 0.f;
#pragma unroll
  for (int n = 0; n < 4; ++n) {
    int col = w * 64 + n * 16 + lr;
    float bias = bz[n];
#pragma unroll
    for (int mt = 0; mt < 4; ++mt)
#pragma unroll
      for (int reg = 0; reg < 4; ++reg) {
        int j = mt * 16 + lh * 4 + reg;
        float rv = fmaxf(acc2[mt][n][reg] + bias, 0.f);
        float rm = rv * alive[j];
        red[n] = domax ? fmaxf(red[n], rm) : (red[n] + rm);
        if (isagent) r_agent[((size_t)b * NA + j) * 256 + col] = (f16)rv;
      }
  }
#pragma unroll
  for (int n = 0; n < 4; ++n) {
    float v = red[n];
    float v1 = __shfl_xor(v, 16, 64);
    v = domax ? fmaxf(v, v1) : v + v1;
    float v2 = __shfl_xor(v, 32, 64);
    v = domax ? fmaxf(v, v2) : v + v2;
    if (lh == 0) r_red[(size_t)bid * 256 + w * 64 + n * 16 + lr] = v;
  }
}

// ---------------------------------------------------------------------------
// K4m: 16 rows per block, grid 128.
//   s_new  = relu([s, r_avr, r_max] @ ra_w + ra_b)   K=384
//   sproj2 = s_new @ ae_w1[256:384]; sproj3 = s_new @ ae_w1[384:512]
// ---------------------------------------------------------------------------
__global__ __launch_bounds__(256) void k4m(const float* __restrict__ s,
                                           const float* __restrict__ r_red,
                                           const float* __restrict__ ra_b,
                                           const f16* __restrict__ pra,
                                           const f16* __restrict__ pae1b,
                                           const f16* __restrict__ pae1c,
                                           float* __restrict__ s_new,
                                           float* __restrict__ sproj2,
                                           float* __restrict__ sproj3) {
  __shared__ f16 x3[16 * 384];  // 12 KB
  __shared__ f16 t2[16 * 128];  // 4 KB
  const int row0 = blockIdx.x * 16;
  const int tid = threadIdx.x;
  const int w = tid >> 6, l = tid & 63, lr = l & 15, lh = l >> 4;

  // stage X = [s | r_avr | r_max] as fp16 swizzled (16 rows x 384)
#pragma unroll
  for (int it = 0; it < 6; ++it) {
    int e = it * 1024 + tid * 4;
    int row = e / 384;
    int c = e - row * 384;
    float4 v;
    if (c < 128) {
      v = *(const float4*)(s + (size_t)(row0 + row) * NH + c);
    } else {
      v = *(const float4*)(r_red + (size_t)(row0 + row) * 256 + (c - 128));
      if (c < 256) { v.x *= (1.f / 64.f); v.y *= (1.f / 64.f); v.z *= (1.f / 64.f); v.w *= (1.f / 64.f); }
    }
    f16x4 hv;
    hv[0] = (f16)v.x; hv[1] = (f16)v.y; hv[2] = (f16)v.z; hv[3] = (f16)v.w;
    unsigned off = (unsigned)((row * 384 + c) * 2) ^ ((unsigned)(row & 7) << 4);
    *(f16x4*)((char*)x3 + off) = hv;
  }
  __syncthreads();

  // ra layer K=384
  f32x4 acc[2];
  acc[0] = (f32x4){0.f, 0.f, 0.f, 0.f};
  acc[1] = (f32x4){0.f, 0.f, 0.f, 0.f};
#pragma unroll
  for (int kt = 0; kt < 12; ++kt) {
    unsigned off = (unsigned)((lr * 384 + kt * 32 + lh * 8) * 2) ^ ((unsigned)(lr & 7) << 4);
    f16x8 aF = *(const f16x8*)((char*)x3 + off);
#pragma unroll
    for (int n = 0; n < 2; ++n) {
      f16x8 bF = *(const f16x8*)(pra + ((size_t)(kt * 8 + w * 2 + n) * 64 + l) * 8);
      acc[n] = __builtin_amdgcn_mfma_f32_16x16x32_f16(aF, bF, acc[n], 0, 0, 0);
    }
  }
#pragma unroll
  for (int n = 0; n < 2; ++n) {
    int h = w * 32 + n * 16 + lr;
    float bias = ra_b[h];
#pragma unroll
    for (int reg = 0; reg < 4; ++reg) {
      int j = lh * 4 + reg;
      float v = fmaxf(acc[n][reg] + bias, 0.f);
      s_new[(size_t)(row0 + j) * NH + h] = v;
      unsigned off = (unsigned)((j * NH + h) * 2) ^ ((unsigned)(j & 7) << 4);
      *(f16*)((char*)t2 + off) = (f16)v;
    }
  }
  __syncthreads();

  // proj2/proj3 K=128 (shared A fragments)
  f32x4 p2[2], p3[2];
  p2[0] = p2[1] = (f32x4){0.f, 0.f, 0.f, 0.f};
  p3[0] = p3[1] = (f32x4){0.f, 0.f, 0.f, 0.f};
#pragma unroll
  for (int kt = 0; kt < 4; ++kt) {
    unsigned off = (unsigned)((lr * NH + kt * 32 + lh * 8) * 2) ^ ((unsigned)(lr & 7) << 4);
    f16x8 aF = *(const f16x8*)((char*)t2 + off);
#pragma unroll
    for (int n = 0; n < 2; ++n) {
      f16x8 b2 = *(const f16x8*)(pae1b + ((size_t)(kt * 8 + w * 2 + n) * 64 + l) * 8);
      f16x8 b3 = *(const f16x8*)(pae1c + ((size_t)(kt * 8 + w * 2 + n) * 64 + l) * 8);
      p2[n] = __builtin_amdgcn_mfma_f32_16x16x32_f16(aF, b2, p2[n], 0, 0, 0);
      p3[n] = __builtin_amdgcn_mfma_f32_16x16x32_f16(aF, b3, p3[n], 0, 0, 0);
    }
  }
#pragma unroll
  for (int n = 0; n < 2; ++n) {
    int h = w * 32 + n * 16 + lr;
#pragma unroll
    for (int reg = 0; reg < 4; ++reg) {
      int j = lh * 4 + reg;
      sproj2[(size_t)(row0 + j) * NH + h] = p2[n][reg];
      sproj3[(size_t)(row0 + j) * NH + h] = p3[n][reg];
    }
  }
}

// ---------------------------------------------------------------------------
// K5 fused: per b -> sel row + passive row (ae-MLP), then assemble outputs.
// One block per b, 256 threads.
// ---------------------------------------------------------------------------
__global__ __launch_bounds__(256) void k5_fused(const float* __restrict__ ae_w1,
                                                const float* __restrict__ ae_b1,
                                                const float* __restrict__ ae_w2,
                                                const float* __restrict__ ae_b2,
                                                const float* __restrict__ action_embed,
                                                const int* __restrict__ action,
                                                const int* __restrict__ agent_id,
                                                const f16* __restrict__ r_agent,
                                                const float* __restrict__ sproj2,
                                                const float* __restrict__ sproj3,
                                                const float* __restrict__ s_new,
                                                float* __restrict__ out_state,
                                                float* __restrict__ out_sel,
                                                float* __restrict__ out_passive) {
  __shared__ float selL[128], pasL[128], rr[256], t[128];
  const int b = blockIdx.x;
  const int tid = threadIdx.x;
  const int h = tid & 127;
  const int act = action[b];
  const int aid = agent_id[0];

  if (act < NE) {
    if (tid < 128) {
      selL[h] = action_embed[act * NH + h];
      pasL[h] = 0.f;
    }
  } else {
    const int jj = act - NE;
    const size_t row = (size_t)b * NA + jj;
    const size_t arow = (size_t)b * NA + aid;
    rr[tid] = (float)r_agent[row * 256 + tid];
    __syncthreads();
    if (tid < 128) {
      float acc = ae_b1[h] + sproj2[row * NH + h] + sproj3[arow * NH + h];
#pragma unroll 4
      for (int k = 0; k < 256; ++k) acc += rr[k] * ae_w1[k * NH + h];
      t[h] = fmaxf(acc, 0.f);
    }
    __syncthreads();
    if (tid < 128) {
      float a_act = ae_b2[h], a_pas = ae_b2[128 + h];
#pragma unroll 4
      for (int k = 0; k < NH; ++k) {
        float tv = t[k];
        a_act += tv * ae_w2[k * 256 + h];
        a_pas += tv * ae_w2[k * 256 + 128 + h];
      }
      selL[h] = fmaxf(a_act, 0.f);
      pasL[h] = fmaxf(a_pas, 0.f);
    }
  }
  __syncthreads();
  if (tid < 128) out_sel[b * NH + h] = selL[h];

  // assemble: 64 rows x 128 cols (2048 float4, 8 iters)
  const int prow = (act >= NE) ? (act - NE) : -1;
#pragma unroll
  for (int it = 0; it < 8; ++it) {
    int q = it * 256 + tid;
    int i = q >> 5;
    int c = (q & 31) * 4;
    size_t idx = ((size_t)b * NA + i) * NH + c;
    float4 st = *(const float4*)(s_new + idx);
    float4 ps = {0.f, 0.f, 0.f, 0.f};
    if (i == prow) {
      ps.x = pasL[c]; ps.y = pasL[c + 1]; ps.z = pasL[c + 2]; ps.w = pasL[c + 3];
      st.x += ps.x; st.y += ps.y; st.z += ps.z; st.w += ps.w;
    }
    if (i == aid) {
      st.x += selL[c]; st.y += selL[c + 1]; st.z += selL[c + 2]; st.w += selL[c + 3];
    }
    *(float4*)(out_state + idx) = st;
    *(float4*)(out_passive + idx) = ps;
  }
}

// ---------------------------------------------------------------------------
extern "C" void kernel_launch(void* const* d_in, const int* in_sizes, int n_in,
                              void* d_out, int out_size, void* d_ws, size_t ws_size,
                              hipStream_t stream) {
  (void)in_sizes; (void)n_in; (void)out_size; (void)ws_size;
  const float* states       = (const float*)d_in[0];
  const float* relations    = (const float*)d_in[1];
  const float* alive_mask   = (const float*)d_in[2];
  const float* se_w1        = (const float*)d_in[3];
  const float* se_b1        = (const float*)d_in[4];
  const float* se_w2        = (const float*)d_in[5];
  const float* se_b2        = (const float*)d_in[6];
  const float* re_w1        = (const float*)d_in[7];
  const float* re_b1        = (const float*)d_in[8];
  const float* re_w2        = (const float*)d_in[9];
  const float* re_b2        = (const float*)d_in[10];
  const float* ra_w         = (const float*)d_in[11];
  const float* ra_b         = (const float*)d_in[12];
  const float* ae_w1        = (const float*)d_in[13];
  const float* ae_b1        = (const float*)d_in[14];
  const float* ae_w2        = (const float*)d_in[15];
  const float* ae_b2        = (const float*)d_in[16];
  const float* action_embed = (const float*)d_in[17];
  const int*   action       = (const int*)d_in[19];
  const int*   agent_id     = (const int*)d_in[20];
  float* out = (float*)d_out;

  // workspace layout (float elements)
  float* wsf       = (float*)d_ws;
  float* s         = wsf;                // 2048*128
  float* sproj1    = wsf + 262144;       // 2048*128
  float* r_red     = wsf + 524288;       // 2048*256 (sum | max)
  float* s_new     = wsf + 1048576;      // 2048*128
  float* sproj2    = wsf + 1310720;      // 2048*128
  float* sproj3    = wsf + 1572864;      // 2048*128
  f16*   wsh       = (f16*)(wsf + 1843200);
  f16*   r_agent   = wsh;                // 32*64*256
  f16*   pk        = wsh + 524288;       // 188416 packed weights
  f16*   pw_re1a   = pk;
  f16*   pw_re2    = pk + 8192;
  f16*   pw_se1    = pk + 40960;
  f16*   pw_se2    = pk + 73728;
  f16*   pw_re1b   = pk + 90112;
  f16*   pw_ra     = pk + 106496;
  f16*   pw_ae1b   = pk + 155648;
  f16*   pw_ae1c   = pk + 172032;

  k0_pack<<<736, 256, 0, stream>>>(re_w1, re_w2, se_w1, se_w2, ra_w, ae_w1, pk);
  k1m<<<128, 256, 0, stream>>>(states, se_b1, se_b2, re_b1, pw_se1, pw_se2, pw_re1b,
                               s, sproj1);
  k3_rel<<<2048, 256, 0, stream>>>(relations, alive_mask, sproj1, re_b2, pw_re1a, pw_re2,
                                   agent_id, r_red, r_agent);
  k4m<<<128, 256, 0, stream>>>(s, r_red, ra_b, pw_ra, pw_ae1b, pw_ae1c,
                               s_new, sproj2, sproj3);
  k5_fused<<<32, 256, 0, stream>>>(ae_w1, ae_b1, ae_w2, ae_b2, action_embed, action,
                                   agent_id, r_agent, sproj2, sproj3, s_new,
                                   out, out + 262144, out + 266240);
}

// Round 6
// 167.560 us; speedup vs baseline: 1.7444x; 1.1421x over previous
//
#include <hip/hip_runtime.h>

// Problem dims
#define NB 32
#define NA 64
#define SLEN 256
#define NH 128
#define RLEN 64
#define NE 16

typedef _Float16 f16;
typedef _Float16 f16x8 __attribute__((ext_vector_type(8)));
typedef _Float16 f16x4 __attribute__((ext_vector_type(4)));
typedef float f32x4 __attribute__((ext_vector_type(4)));

__device__ inline f16x8 cvt8(float4 a, float4 b) {
  f16x8 r;
  r[0] = (f16)a.x; r[1] = (f16)a.y; r[2] = (f16)a.z; r[3] = (f16)a.w;
  r[4] = (f16)b.x; r[5] = (f16)b.y; r[6] = (f16)b.z; r[7] = (f16)b.w;
  return r;
}

// ---------------------------------------------------------------------------
// K0: pack all GEMM weights into fp16 MFMA B-fragment order.
// packed[(kt*NT+nt)*512 + l*8 + t] = W[ro + kt*32 + (l>>4)*8 + t][nt*16 + (l&15)]
// ---------------------------------------------------------------------------
__global__ __launch_bounds__(256) void k0_pack(const float* __restrict__ re_w1,
                                               const float* __restrict__ re_w2,
                                               const float* __restrict__ se_w1,
                                               const float* __restrict__ se_w2,
                                               const float* __restrict__ ra_w,
                                               const float* __restrict__ ae_w1,
                                               const float* __restrict__ ae_w2,
                                               f16* __restrict__ pk) {
  int idx = blockIdx.x * 256 + threadIdx.x;
  const float* src;
  int ro, N, ld, base;
  if (idx < 8192)        { src = re_w1; ro = 0;   N = 128; ld = 128; base = 0; }
  else if (idx < 40960)  { src = re_w2; ro = 0;   N = 256; ld = 256; base = 8192; }
  else if (idx < 73728)  { src = se_w1; ro = 0;   N = 128; ld = 128; base = 40960; }
  else if (idx < 90112)  { src = se_w2; ro = 0;   N = 128; ld = 128; base = 73728; }
  else if (idx < 106496) { src = re_w1; ro = 64;  N = 128; ld = 128; base = 90112; }
  else if (idx < 155648) { src = ra_w;  ro = 0;   N = 128; ld = 128; base = 106496; }
  else if (idx < 172032) { src = ae_w1; ro = 256; N = 128; ld = 128; base = 155648; }
  else if (idx < 188416) { src = ae_w1; ro = 384; N = 128; ld = 128; base = 172032; }
  else if (idx < 221184) { src = ae_w1; ro = 0;   N = 128; ld = 128; base = 188416; }
  else if (idx < 253952) { src = ae_w2; ro = 0;   N = 256; ld = 256; base = 221184; }
  else return;
  int li = idx - base;
  int t = li & 7, l = (li >> 3) & 63, rem = li >> 9;
  int NT = N >> 4;
  int nt = rem % NT, kt = rem / NT;
  int k = kt * 32 + (l >> 4) * 8 + t;
  int n = nt * 16 + (l & 15);
  pk[idx] = (f16)src[(size_t)(ro + k) * ld + n];
}

// ---------------------------------------------------------------------------
// K1m: s-MLP + packed sproj1. 16 rows per block, grid 128, 4 waves.
//   t = relu(states @ se_w1 + se_b1)   K=256
//   s = relu(t @ se_w2 + se_b2)        K=128
//   sp_pk = (s @ re_w1[64:192] + re_b1), stored in k3's C-fragment order:
//   sp_pk[((b*4 + mt)*8 + w*2+n)*64 + l][reg] (float4 per thread-frag)
// ---------------------------------------------------------------------------
__global__ __launch_bounds__(256) void k1m(const float* __restrict__ states,
                                           const float* __restrict__ se_b1,
                                           const float* __restrict__ se_b2,
                                           const float* __restrict__ re_b1,
                                           const f16* __restrict__ pse1,
                                           const f16* __restrict__ pse2,
                                           const f16* __restrict__ pre1b,
                                           float* __restrict__ s_out,
                                           float* __restrict__ sp_pk) {
  __shared__ f16 t1[16 * 128];
  __shared__ f16 t2[16 * 128];
  const int row0 = blockIdx.x * 16;
  const int tid = threadIdx.x;
  const int w = tid >> 6, l = tid & 63, lr = l & 15, lh = l >> 4;

  f32x4 acc[2];
  acc[0] = (f32x4){0.f, 0.f, 0.f, 0.f};
  acc[1] = (f32x4){0.f, 0.f, 0.f, 0.f};

  // layer1 K=256
#pragma unroll
  for (int kt = 0; kt < 8; ++kt) {
    const float* p = states + (size_t)(row0 + lr) * SLEN + kt * 32 + lh * 8;
    f16x8 aF = cvt8(*(const float4*)p, *(const float4*)(p + 4));
#pragma unroll
    for (int n = 0; n < 2; ++n) {
      f16x8 bF = *(const f16x8*)(pse1 + ((size_t)(kt * 8 + w * 2 + n) * 64 + l) * 8);
      acc[n] = __builtin_amdgcn_mfma_f32_16x16x32_f16(aF, bF, acc[n], 0, 0, 0);
    }
  }
#pragma unroll
  for (int n = 0; n < 2; ++n) {
    int h = w * 32 + n * 16 + lr;
    float bias = se_b1[h];
#pragma unroll
    for (int reg = 0; reg < 4; ++reg) {
      int j = lh * 4 + reg;
      float v = fmaxf(acc[n][reg] + bias, 0.f);
      unsigned off = (unsigned)((j * NH + h) * 2) ^ ((unsigned)(j & 7) << 4);
      *(f16*)((char*)t1 + off) = (f16)v;
    }
  }
  __syncthreads();

  // layer2 K=128
  acc[0] = (f32x4){0.f, 0.f, 0.f, 0.f};
  acc[1] = (f32x4){0.f, 0.f, 0.f, 0.f};
#pragma unroll
  for (int kt = 0; kt < 4; ++kt) {
    unsigned off = (unsigned)((lr * NH + kt * 32 + lh * 8) * 2) ^ ((unsigned)(lr & 7) << 4);
    f16x8 aF = *(const f16x8*)((char*)t1 + off);
#pragma unroll
    for (int n = 0; n < 2; ++n) {
      f16x8 bF = *(const f16x8*)(pse2 + ((size_t)(kt * 8 + w * 2 + n) * 64 + l) * 8);
      acc[n] = __builtin_amdgcn_mfma_f32_16x16x32_f16(aF, bF, acc[n], 0, 0, 0);
    }
  }
#pragma unroll
  for (int n = 0; n < 2; ++n) {
    int h = w * 32 + n * 16 + lr;
    float bias = se_b2[h];
#pragma unroll
    for (int reg = 0; reg < 4; ++reg) {
      int j = lh * 4 + reg;
      float v = fmaxf(acc[n][reg] + bias, 0.f);
      s_out[(size_t)(row0 + j) * NH + h] = v;
      unsigned off = (unsigned)((j * NH + h) * 2) ^ ((unsigned)(j & 7) << 4);
      *(f16*)((char*)t2 + off) = (f16)v;
    }
  }
  __syncthreads();

  // proj K=128: sproj1 = s @ re_w1b + re_b1, packed store
  acc[0] = (f32x4){0.f, 0.f, 0.f, 0.f};
  acc[1] = (f32x4){0.f, 0.f, 0.f, 0.f};
#pragma unroll
  for (int kt = 0; kt < 4; ++kt) {
    unsigned off = (unsigned)((lr * NH + kt * 32 + lh * 8) * 2) ^ ((unsigned)(lr & 7) << 4);
    f16x8 aF = *(const f16x8*)((char*)t2 + off);
#pragma unroll
    for (int n = 0; n < 2; ++n) {
      f16x8 bF = *(const f16x8*)(pre1b + ((size_t)(kt * 8 + w * 2 + n) * 64 + l) * 8);
      acc[n] = __builtin_amdgcn_mfma_f32_16x16x32_f16(aF, bF, acc[n], 0, 0, 0);
    }
  }
  const int bb = row0 >> 6;          // batch index
  const int mtile = (row0 & 63) >> 4; // which 16-row band of the 64-row b-tile
#pragma unroll
  for (int n = 0; n < 2; ++n) {
    int h = w * 32 + n * 16 + lr;
    float bias = re_b1[h];
    float4 outv;
#pragma unroll
    for (int reg = 0; reg < 4; ++reg) outv[reg] = acc[n][reg] + bias;
    *(float4*)(sp_pk + ((size_t)((bb * 4 + mtile) * 8 + w * 2 + n) * 64 + l) * 4) = outv;
  }
}

// ---------------------------------------------------------------------------
// K3 v4: one (b,i) tile per block, grid 2048. No sproj1 LDS staging:
// sproj1 read as packed C-fragments straight from L2. LDS = 16.3 KB,
// one barrier.
// ---------------------------------------------------------------------------
__global__ __launch_bounds__(256) void k3_rel(const float* __restrict__ relations,
                                              const float* __restrict__ alive_mask,
                                              const float* __restrict__ sp_pk,
                                              const float* __restrict__ re_b2,
                                              const f16* __restrict__ pw1,
                                              const f16* __restrict__ pw2,
                                              const int* __restrict__ agent_id,
                                              float* __restrict__ r_red,
                                              f16* __restrict__ r_agent) {
  __shared__ f16 tl[64 * 128];  // 16 KB
  __shared__ float alive[NA];
  const int bid = blockIdx.x;  // 0..2047
  const int b = bid >> 6, i = bid & 63;
  const int tid = threadIdx.x;
  const int w = tid >> 6, l = tid & 63, lr = l & 15, lh = l >> 4;

  if (tid < 64) alive[tid] = alive_mask[b * NA + tid];
  float bz[4];
#pragma unroll
  for (int n = 0; n < 4; ++n) bz[n] = re_b2[w * 64 + n * 16 + lr];

  // layer1 inputs: relations rows + B fragments + packed sproj1 fragments
  const float* relp = relations + (size_t)bid * NA * RLEN;
  f16x8 a1[4][2];
#pragma unroll
  for (int mt = 0; mt < 4; ++mt)
#pragma unroll
    for (int kt = 0; kt < 2; ++kt) {
      const float* p = relp + (mt * 16 + lr) * RLEN + kt * 32 + lh * 8;
      a1[mt][kt] = cvt8(*(const float4*)p, *(const float4*)(p + 4));
    }
  f16x8 b1f[2][2];
#pragma unroll
  for (int kt = 0; kt < 2; ++kt)
#pragma unroll
    for (int n = 0; n < 2; ++n)
      b1f[kt][n] = *(const f16x8*)(pw1 + ((size_t)(kt * 8 + w * 2 + n) * 64 + l) * 8);
  float4 sp4[4][2];
  {
    const float* spp = sp_pk + (size_t)b * 8192;
#pragma unroll
    for (int mt = 0; mt < 4; ++mt)
#pragma unroll
      for (int n = 0; n < 2; ++n)
        sp4[mt][n] = *(const float4*)(spp + (size_t)((mt * 8 + w * 2 + n) * 64 + l) * 4);
  }

  f32x4 acc1[4][2];
#pragma unroll
  for (int mt = 0; mt < 4; ++mt)
#pragma unroll
    for (int n = 0; n < 2; ++n) acc1[mt][n] = (f32x4){0.f, 0.f, 0.f, 0.f};
#pragma unroll
  for (int kt = 0; kt < 2; ++kt)
#pragma unroll
    for (int mt = 0; mt < 4; ++mt)
#pragma unroll
      for (int n = 0; n < 2; ++n)
        acc1[mt][n] = __builtin_amdgcn_mfma_f32_16x16x32_f16(a1[mt][kt], b1f[kt][n],
                                                             acc1[mt][n], 0, 0, 0);

  // epilogue1: + sproj1 fragment (re_b1 folded), relu, fp16 swizzled LDS
#pragma unroll
  for (int mt = 0; mt < 4; ++mt)
#pragma unroll
    for (int n = 0; n < 2; ++n) {
      int h = w * 32 + n * 16 + lr;
#pragma unroll
      for (int reg = 0; reg < 4; ++reg) {
        int j = mt * 16 + lh * 4 + reg;
        float v = fmaxf(acc1[mt][n][reg] + sp4[mt][n][reg], 0.f);
        unsigned off = (unsigned)((j * NH + h) * 2) ^ ((unsigned)(j & 7) << 4);
        *(f16*)((char*)tl + off) = (f16)v;
      }
    }
  __syncthreads();

  // layer2: wave w owns output cols [w*64, w*64+64)
  f32x4 acc2[4][4];
#pragma unroll
  for (int mt = 0; mt < 4; ++mt)
#pragma unroll
    for (int n = 0; n < 4; ++n) acc2[mt][n] = (f32x4){0.f, 0.f, 0.f, 0.f};
#pragma unroll
  for (int kt2 = 0; kt2 < 4; ++kt2) {
    f16x8 a2[4];
#pragma unroll
    for (int mt = 0; mt < 4; ++mt) {
      int row = mt * 16 + lr;
      unsigned off = (unsigned)((row * 256 + kt2 * 64 + lh * 16)) ^ ((unsigned)(row & 7) << 4);
      a2[mt] = *(const f16x8*)((char*)tl + off);
    }
    f16x8 b2f[4];
#pragma unroll
    for (int n = 0; n < 4; ++n)
      b2f[n] = *(const f16x8*)(pw2 + ((size_t)(kt2 * 16 + w * 4 + n) * 64 + l) * 8);
#pragma unroll
    for (int mt = 0; mt < 4; ++mt)
#pragma unroll
      for (int n = 0; n < 4; ++n)
        acc2[mt][n] = __builtin_amdgcn_mfma_f32_16x16x32_f16(a2[mt], b2f[n], acc2[mt][n], 0, 0, 0);
  }

  // epilogue2: bias+relu, masked sum/max over j, agent slice store
  const int aid = agent_id[0];
  const bool isagent = (i == aid);
  const bool domax = (w >= 2);
  float red[4];
#pragma unroll
  for (int n = 0; n < 4; ++n) red[n] = 0.f;
#pragma unroll
  for (int n = 0; n < 4; ++n) {
    int col = w * 64 + n * 16 + lr;
    float bias = bz[n];
#pragma unroll
    for (int mt = 0; mt < 4; ++mt)
#pragma unroll
      for (int reg = 0; reg < 4; ++reg) {
        int j = mt * 16 + lh * 4 + reg;
        float rv = fmaxf(acc2[mt][n][reg] + bias, 0.f);
        float rm = rv * alive[j];
        red[n] = domax ? fmaxf(red[n], rm) : (red[n] + rm);
        if (isagent) r_agent[((size_t)b * NA + j) * 256 + col] = (f16)rv;
      }
  }
#pragma unroll
  for (int n = 0; n < 4; ++n) {
    float v = red[n];
    float v1 = __shfl_xor(v, 16, 64);
    v = domax ? fmaxf(v, v1) : v + v1;
    float v2 = __shfl_xor(v, 32, 64);
    v = domax ? fmaxf(v, v2) : v + v2;
    if (lh == 0) r_red[(size_t)bid * 256 + w * 64 + n * 16 + lr] = v;
  }
}

// ---------------------------------------------------------------------------
// K4m: 16 rows per block, grid 128.
//   s_new  = relu([s, r_avr, r_max] @ ra_w + ra_b)   K=384
//   sproj2 = s_new @ ae_w1[256:384]; sproj3 = s_new @ ae_w1[384:512]
// ---------------------------------------------------------------------------
__global__ __launch_bounds__(256) void k4m(const float* __restrict__ s,
                                           const float* __restrict__ r_red,
                                           const float* __restrict__ ra_b,
                                           const f16* __restrict__ pra,
                                           const f16* __restrict__ pae1b,
                                           const f16* __restrict__ pae1c,
                                           float* __restrict__ s_new,
                                           float* __restrict__ sproj2,
                                           float* __restrict__ sproj3) {
  __shared__ f16 x3[16 * 384];  // 12 KB
  __shared__ f16 t2[16 * 128];  // 4 KB
  const int row0 = blockIdx.x * 16;
  const int tid = threadIdx.x;
  const int w = tid >> 6, l = tid & 63, lr = l & 15, lh = l >> 4;

  // stage X = [s | r_avr | r_max] as fp16 swizzled (16 rows x 384)
#pragma unroll
  for (int it = 0; it < 6; ++it) {
    int e = it * 1024 + tid * 4;
    int row = e / 384;
    int c = e - row * 384;
    float4 v;
    if (c < 128) {
      v = *(const float4*)(s + (size_t)(row0 + row) * NH + c);
    } else {
      v = *(const float4*)(r_red + (size_t)(row0 + row) * 256 + (c - 128));
      if (c < 256) { v.x *= (1.f / 64.f); v.y *= (1.f / 64.f); v.z *= (1.f / 64.f); v.w *= (1.f / 64.f); }
    }
    f16x4 hv;
    hv[0] = (f16)v.x; hv[1] = (f16)v.y; hv[2] = (f16)v.z; hv[3] = (f16)v.w;
    unsigned off = (unsigned)((row * 384 + c) * 2) ^ ((unsigned)(row & 7) << 4);
    *(f16x4*)((char*)x3 + off) = hv;
  }
  __syncthreads();

  // ra layer K=384
  f32x4 acc[2];
  acc[0] = (f32x4){0.f, 0.f, 0.f, 0.f};
  acc[1] = (f32x4){0.f, 0.f, 0.f, 0.f};
#pragma unroll
  for (int kt = 0; kt < 12; ++kt) {
    unsigned off = (unsigned)((lr * 384 + kt * 32 + lh * 8) * 2) ^ ((unsigned)(lr & 7) << 4);
    f16x8 aF = *(const f16x8*)((char*)x3 + off);
#pragma unroll
    for (int n = 0; n < 2; ++n) {
      f16x8 bF = *(const f16x8*)(pra + ((size_t)(kt * 8 + w * 2 + n) * 64 + l) * 8);
      acc[n] = __builtin_amdgcn_mfma_f32_16x16x32_f16(aF, bF, acc[n], 0, 0, 0);
    }
  }
#pragma unroll
  for (int n = 0; n < 2; ++n) {
    int h = w * 32 + n * 16 + lr;
    float bias = ra_b[h];
#pragma unroll
    for (int reg = 0; reg < 4; ++reg) {
      int j = lh * 4 + reg;
      float v = fmaxf(acc[n][reg] + bias, 0.f);
      s_new[(size_t)(row0 + j) * NH + h] = v;
      unsigned off = (unsigned)((j * NH + h) * 2) ^ ((unsigned)(j & 7) << 4);
      *(f16*)((char*)t2 + off) = (f16)v;
    }
  }
  __syncthreads();

  // proj2/proj3 K=128 (shared A fragments)
  f32x4 p2[2], p3[2];
  p2[0] = p2[1] = (f32x4){0.f, 0.f, 0.f, 0.f};
  p3[0] = p3[1] = (f32x4){0.f, 0.f, 0.f, 0.f};
#pragma unroll
  for (int kt = 0; kt < 4; ++kt) {
    unsigned off = (unsigned)((lr * NH + kt * 32 + lh * 8) * 2) ^ ((unsigned)(lr & 7) << 4);
    f16x8 aF = *(const f16x8*)((char*)t2 + off);
#pragma unroll
    for (int n = 0; n < 2; ++n) {
      f16x8 b2 = *(const f16x8*)(pae1b + ((size_t)(kt * 8 + w * 2 + n) * 64 + l) * 8);
      f16x8 b3 = *(const f16x8*)(pae1c + ((size_t)(kt * 8 + w * 2 + n) * 64 + l) * 8);
      p2[n] = __builtin_amdgcn_mfma_f32_16x16x32_f16(aF, b2, p2[n], 0, 0, 0);
      p3[n] = __builtin_amdgcn_mfma_f32_16x16x32_f16(aF, b3, p3[n], 0, 0, 0);
    }
  }
#pragma unroll
  for (int n = 0; n < 2; ++n) {
    int h = w * 32 + n * 16 + lr;
#pragma unroll
    for (int reg = 0; reg < 4; ++reg) {
      int j = lh * 4 + reg;
      sproj2[(size_t)(row0 + j) * NH + h] = p2[n][reg];
      sproj3[(size_t)(row0 + j) * NH + h] = p3[n][reg];
    }
  }
}

// ---------------------------------------------------------------------------
// Kae: batched ae-MLP over the agent slice: all (b,j) rows. 16 rows/block,
// grid 128. ae_full[row][0:128]=active, [128:256]=passive (both relu'd).
//   u = relu(r_agent[row] @ ae_w1[0:256] + sproj2[row] + sproj3[b,aid] + ae_b1)
//   ae = relu(u @ ae_w2 + ae_b2)
// ---------------------------------------------------------------------------
__global__ __launch_bounds__(256) void kae(const f16* __restrict__ r_agent,
                                           const float* __restrict__ sproj2,
                                           const float* __restrict__ sproj3,
                                           const float* __restrict__ ae_b1,
                                           const float* __restrict__ ae_b2,
                                           const f16* __restrict__ pae1a,
                                           const f16* __restrict__ pae2,
                                           const int* __restrict__ agent_id,
                                           float* __restrict__ ae_full) {
  __shared__ f16 t1[16 * 128];
  const int row0 = blockIdx.x * 16;
  const int b = row0 >> 6;
  const int tid = threadIdx.x;
  const int w = tid >> 6, l = tid & 63, lr = l & 15, lh = l >> 4;
  const int aid = agent_id[0];

  // layer1 K=256 (A = fp16 r_agent rows, direct load)
  f32x4 acc[2];
  acc[0] = (f32x4){0.f, 0.f, 0.f, 0.f};
  acc[1] = (f32x4){0.f, 0.f, 0.f, 0.f};
#pragma unroll
  for (int kt = 0; kt < 8; ++kt) {
    f16x8 aF = *(const f16x8*)(r_agent + (size_t)(row0 + lr) * 256 + kt * 32 + lh * 8);
#pragma unroll
    for (int n = 0; n < 2; ++n) {
      f16x8 bF = *(const f16x8*)(pae1a + ((size_t)(kt * 8 + w * 2 + n) * 64 + l) * 8);
      acc[n] = __builtin_amdgcn_mfma_f32_16x16x32_f16(aF, bF, acc[n], 0, 0, 0);
    }
  }
#pragma unroll
  for (int n = 0; n < 2; ++n) {
    int h = w * 32 + n * 16 + lr;
    float base = ae_b1[h] + sproj3[((size_t)b * NA + aid) * NH + h];
#pragma unroll
    for (int reg = 0; reg < 4; ++reg) {
      int j = lh * 4 + reg;
      float v = fmaxf(acc[n][reg] + base + sproj2[(size_t)(row0 + j) * NH + h], 0.f);
      unsigned off = (unsigned)((j * NH + h) * 2) ^ ((unsigned)(j & 7) << 4);
      *(f16*)((char*)t1 + off) = (f16)v;
    }
  }
  __syncthreads();

  // layer2 K=128, N=256: wave w owns cols [w*64, w*64+64)
  f32x4 acc2[4];
#pragma unroll
  for (int n = 0; n < 4; ++n) acc2[n] = (f32x4){0.f, 0.f, 0.f, 0.f};
#pragma unroll
  for (int kt = 0; kt < 4; ++kt) {
    unsigned off = (unsigned)((lr * NH + kt * 32 + lh * 8) * 2) ^ ((unsigned)(lr & 7) << 4);
    f16x8 aF = *(const f16x8*)((char*)t1 + off);
#pragma unroll
    for (int n = 0; n < 4; ++n) {
      f16x8 bF = *(const f16x8*)(pae2 + ((size_t)(kt * 16 + w * 4 + n) * 64 + l) * 8);
      acc2[n] = __builtin_amdgcn_mfma_f32_16x16x32_f16(aF, bF, acc2[n], 0, 0, 0);
    }
  }
#pragma unroll
  for (int n = 0; n < 4; ++n) {
    int col = w * 64 + n * 16 + lr;
    float bias = ae_b2[col];
#pragma unroll
    for (int reg = 0; reg < 4; ++reg) {
      int j = lh * 4 + reg;
      ae_full[(size_t)(row0 + j) * 256 + col] = fmaxf(acc2[n][reg] + bias, 0.f);
    }
  }
}

// ---------------------------------------------------------------------------
// K5g: pure gather + assemble. One block per b, 256 threads.
// ---------------------------------------------------------------------------
__global__ __launch_bounds__(256) void k5g(const float* __restrict__ action_embed,
                                           const int* __restrict__ action,
                                           const int* __restrict__ agent_id,
                                           const float* __restrict__ ae_full,
                                           const float* __restrict__ s_new,
                                           float* __restrict__ out_state,
                                           float* __restrict__ out_sel,
                                           float* __restrict__ out_passive) {
  __shared__ float selL[128], pasL[128];
  const int b = blockIdx.x;
  const int tid = threadIdx.x;
  const int h = tid & 127;
  const int act = action[b];
  const int aid = agent_id[0];

  if (tid < 128) {
    float sv, pv;
    if (act < NE) {
      sv = action_embed[act * NH + h];
      pv = 0.f;
    } else {
      size_t r = (size_t)(b * NA + act - NE) * 256;
      sv = ae_full[r + h];
      pv = ae_full[r + 128 + h];
    }
    selL[h] = sv;
    pasL[h] = pv;
    out_sel[b * NH + h] = sv;
  }
  __syncthreads();

  const int prow = (act >= NE) ? (act - NE) : -1;
#pragma unroll
  for (int it = 0; it < 8; ++it) {
    int q = it * 256 + tid;
    int i = q >> 5;
    int c = (q & 31) * 4;
    size_t idx = ((size_t)b * NA + i) * NH + c;
    float4 st = *(const float4*)(s_new + idx);
    float4 ps = {0.f, 0.f, 0.f, 0.f};
    if (i == prow) {
      ps.x = pasL[c]; ps.y = pasL[c + 1]; ps.z = pasL[c + 2]; ps.w = pasL[c + 3];
      st.x += ps.x; st.y += ps.y; st.z += ps.z; st.w += ps.w;
    }
    if (i == aid) {
      st.x += selL[c]; st.y += selL[c + 1]; st.z += selL[c + 2]; st.w += selL[c + 3];
    }
    *(float4*)(out_state + idx) = st;
    *(float4*)(out_passive + idx) = ps;
  }
}

// ---------------------------------------------------------------------------
extern "C" void kernel_launch(void* const* d_in, const int* in_sizes, int n_in,
                              void* d_out, int out_size, void* d_ws, size_t ws_size,
                              hipStream_t stream) {
  (void)in_sizes; (void)n_in; (void)out_size; (void)ws_size;
  const float* states       = (const float*)d_in[0];
  const float* relations    = (const float*)d_in[1];
  const float* alive_mask   = (const float*)d_in[2];
  const float* se_w1        = (const float*)d_in[3];
  const float* se_b1        = (const float*)d_in[4];
  const float* se_w2        = (const float*)d_in[5];
  const float* se_b2        = (const float*)d_in[6];
  const float* re_w1        = (const float*)d_in[7];
  const float* re_b1        = (const float*)d_in[8];
  const float* re_w2        = (const float*)d_in[9];
  const float* re_b2        = (const float*)d_in[10];
  const float* ra_w         = (const float*)d_in[11];
  const float* ra_b         = (const float*)d_in[12];
  const float* ae_w1        = (const float*)d_in[13];
  const float* ae_b1        = (const float*)d_in[14];
  const float* ae_w2        = (const float*)d_in[15];
  const float* ae_b2        = (const float*)d_in[16];
  const float* action_embed = (const float*)d_in[17];
  const int*   action       = (const int*)d_in[19];
  const int*   agent_id     = (const int*)d_in[20];
  float* out = (float*)d_out;

  // workspace layout (float elements)
  float* wsf     = (float*)d_ws;
  float* s       = wsf;               // 262144
  float* sp_pk   = wsf + 262144;      // 262144 (32 b x 4 mt x 8 ng x 64 l x 4)
  float* r_red   = wsf + 524288;      // 524288 (2048 x 256: sum | max)
  float* s_new   = wsf + 1048576;     // 262144
  float* sproj2  = wsf + 1310720;     // 262144
  float* sproj3  = wsf + 1572864;     // 262144
  float* ae_full = wsf + 1835008;     // 524288 (2048 x 256: active | passive)
  f16*   wsh     = (f16*)(wsf + 2359296);
  f16*   r_agent = wsh;               // 524288 f16
  f16*   pk      = wsh + 524288;      // 253952 f16 packed weights
  f16*   pw_re1a = pk;
  f16*   pw_re2  = pk + 8192;
  f16*   pw_se1  = pk + 40960;
  f16*   pw_se2  = pk + 73728;
  f16*   pw_re1b = pk + 90112;
  f16*   pw_ra   = pk + 106496;
  f16*   pw_ae1b = pk + 155648;
  f16*   pw_ae1c = pk + 172032;
  f16*   pw_ae1a = pk + 188416;
  f16*   pw_ae2  = pk + 221184;

  k0_pack<<<992, 256, 0, stream>>>(re_w1, re_w2, se_w1, se_w2, ra_w, ae_w1, ae_w2, pk);
  k1m<<<128, 256, 0, stream>>>(states, se_b1, se_b2, re_b1, pw_se1, pw_se2, pw_re1b,
                               s, sp_pk);
  k3_rel<<<2048, 256, 0, stream>>>(relations, alive_mask, sp_pk, re_b2, pw_re1a, pw_re2,
                                   agent_id, r_red, r_agent);
  k4m<<<128, 256, 0, stream>>>(s, r_red, ra_b, pw_ra, pw_ae1b, pw_ae1c,
                               s_new, sproj2, sproj3);
  kae<<<128, 256, 0, stream>>>(r_agent, sproj2, sproj3, ae_b1, ae_b2, pw_ae1a, pw_ae2,
                               agent_id, ae_full);
  k5g<<<32, 256, 0, stream>>>(action_embed, action, agent_id, ae_full, s_new,
                              out, out + 262144, out + 266240);
}